// Round 1
// baseline (1059.348 us; speedup 1.0000x reference)
//
#include <hip/hip_runtime.h>
#include <hip/hip_bf16.h>
#include <math.h>

#define DIM      1024
#define D_STATE  64
#define D_CONV   4
#define N_HEADS  8
#define D_INNER  2048
#define HEAD_DIM 256
#define NPROJ    4232      // 2048 + 2048 + 8 + 64 + 64
#define BATCH    2
#define SEQ      1024
#define M_ROWS   (BATCH * SEQ)   // 2048
#define OFF_Z    0
#define OFF_XC   2048
#define OFF_DT   4096
#define OFF_B    4104
#define OFF_C    4168

// ---------------------------------------------------------------------------
// fp32 tiled GEMM: C[M,N] = A[M,K] @ Bm[N,K]^T   (both operands K-contiguous)
// BM=BN=128, BK=16, 256 threads, 8x8 per-thread tile.
// M, K multiples of tile; N edge guarded (N % 8 == 0 assumed for stores).
// ---------------------------------------------------------------------------
template<int BM, int BN, int BK>
__global__ __launch_bounds__(256) void gemm_abt(const float* __restrict__ A,
                                                const float* __restrict__ Bm,
                                                float* __restrict__ C,
                                                int M, int N, int K) {
    __shared__ float As[BK][BM + 4];
    __shared__ float Bs[BK][BN + 4];

    const int tid = threadIdx.x;
    const int tx  = tid & 15;        // 0..15  -> col group
    const int ty  = tid >> 4;        // 0..15  -> row group
    const int m0  = blockIdx.y * BM;
    const int n0  = blockIdx.x * BN;

    float acc[8][8];
#pragma unroll
    for (int i = 0; i < 8; ++i)
#pragma unroll
        for (int j = 0; j < 8; ++j) acc[i][j] = 0.f;

    for (int k0 = 0; k0 < K; k0 += BK) {
        // stage A tile (BM x BK) transposed into As[k][m]
#pragma unroll
        for (int f = tid; f < BM * (BK / 4); f += 256) {
            int row = f >> 2, c4 = f & 3;
            float4 v = *(const float4*)&A[(size_t)(m0 + row) * K + k0 + c4 * 4];
            As[c4 * 4 + 0][row] = v.x;
            As[c4 * 4 + 1][row] = v.y;
            As[c4 * 4 + 2][row] = v.z;
            As[c4 * 4 + 3][row] = v.w;
        }
        // stage B tile (BN x BK) transposed into Bs[k][n], guard n edge
#pragma unroll
        for (int f = tid; f < BN * (BK / 4); f += 256) {
            int row = f >> 2, c4 = f & 3;
            float4 v = make_float4(0.f, 0.f, 0.f, 0.f);
            if (n0 + row < N)
                v = *(const float4*)&Bm[(size_t)(n0 + row) * K + k0 + c4 * 4];
            Bs[c4 * 4 + 0][row] = v.x;
            Bs[c4 * 4 + 1][row] = v.y;
            Bs[c4 * 4 + 2][row] = v.z;
            Bs[c4 * 4 + 3][row] = v.w;
        }
        __syncthreads();
#pragma unroll
        for (int kk = 0; kk < BK; ++kk) {
            float a[8], b[8];
            float4 a0 = *(const float4*)&As[kk][ty * 8];
            float4 a1 = *(const float4*)&As[kk][ty * 8 + 4];
            float4 b0 = *(const float4*)&Bs[kk][tx * 8];
            float4 b1 = *(const float4*)&Bs[kk][tx * 8 + 4];
            a[0]=a0.x; a[1]=a0.y; a[2]=a0.z; a[3]=a0.w;
            a[4]=a1.x; a[5]=a1.y; a[6]=a1.z; a[7]=a1.w;
            b[0]=b0.x; b[1]=b0.y; b[2]=b0.z; b[3]=b0.w;
            b[4]=b1.x; b[5]=b1.y; b[6]=b1.z; b[7]=b1.w;
#pragma unroll
            for (int i = 0; i < 8; ++i)
#pragma unroll
                for (int j = 0; j < 8; ++j)
                    acc[i][j] = fmaf(a[i], b[j], acc[i][j]);
        }
        __syncthreads();
    }

    const int col0 = n0 + tx * 8;
#pragma unroll
    for (int i = 0; i < 8; ++i) {
        int row = m0 + ty * 8 + i;
        if (col0 < N) {
            float4 v0 = make_float4(acc[i][0], acc[i][1], acc[i][2], acc[i][3]);
            float4 v1 = make_float4(acc[i][4], acc[i][5], acc[i][6], acc[i][7]);
            *(float4*)&C[(size_t)row * N + col0]     = v0;
            *(float4*)&C[(size_t)row * N + col0 + 4] = v1;
        }
    }
}

// ---------------------------------------------------------------------------
// depthwise causal conv (k=4) + SiLU over the xc slice -> xh
// ---------------------------------------------------------------------------
__global__ __launch_bounds__(256) void conv_silu_kernel(const float* __restrict__ zx,
                                                        const float* __restrict__ conv_w,
                                                        const float* __restrict__ conv_b,
                                                        float* __restrict__ xh) {
    int idx = blockIdx.x * 256 + threadIdx.x;       // over M_ROWS * D_INNER
    int c = idx & (D_INNER - 1);
    int m = idx >> 11;
    int l = m & (SEQ - 1);
    float acc = conv_b[c];
#pragma unroll
    for (int k = 0; k < D_CONV; ++k) {
        int lj = l + k - (D_CONV - 1);
        if (lj >= 0)
            acc = fmaf(zx[(size_t)(m + k - (D_CONV - 1)) * NPROJ + OFF_XC + c],
                       conv_w[c * D_CONV + k], acc);
    }
    float s = acc / (1.f + expf(-acc));   // silu
    xh[idx] = s;
}

// ---------------------------------------------------------------------------
// dt = softplus(logits + dt_bias); a_bar = exp(dt * -exp(A_log))
// ---------------------------------------------------------------------------
__global__ __launch_bounds__(256) void dt_abar_kernel(const float* __restrict__ zx,
                                                      const float* __restrict__ dt_bias,
                                                      const float* __restrict__ A_log,
                                                      float* __restrict__ abar) {
    int idx = blockIdx.x * 256 + threadIdx.x;       // over M_ROWS * N_HEADS
    int h = idx & (N_HEADS - 1);
    int m = idx >> 3;
    float v = zx[(size_t)m * NPROJ + OFF_DT + h] + dt_bias[h];
    float dt = (v > 20.f) ? v : log1pf(expf(v));
    float A = -expf(A_log[h]);
    abar[idx] = expf(dt * A);
}

// ---------------------------------------------------------------------------
// selective scan. block = (b, head, quarter-of-head-dim); 256 threads.
// thread t: d_local = t>>2 (64 d per block), g = t&3 (16 states per lane).
// h-state lives in 16 VGPRs; B/C/x/abar staged per 32-step chunk in LDS.
// ---------------------------------------------------------------------------
#define SCHUNK 32
__global__ __launch_bounds__(256) void scan_kernel(const float* __restrict__ zx,
                                                   const float* __restrict__ xh,
                                                   const float* __restrict__ abar,
                                                   float* __restrict__ yscan) {
    const int blk = blockIdx.x;          // 0..63
    const int dq = blk & 3;
    const int bh = blk >> 2;
    const int hh = bh & (N_HEADS - 1);
    const int b  = bh >> 3;
    const int t  = threadIdx.x;
    const int d_local = t >> 2;
    const int g = t & 3;

    __shared__ float aS[SCHUNK];
    __shared__ float bS[SCHUNK][D_STATE];
    __shared__ float cS[SCHUNK][D_STATE];
    __shared__ float xS[SCHUNK][64];

    float hst[16];
#pragma unroll
    for (int i = 0; i < 16; ++i) hst[i] = 0.f;

    const int m0base = b * SEQ;
    const int xcol = hh * HEAD_DIM + dq * 64;

    for (int ch = 0; ch < SEQ / SCHUNK; ++ch) {
        const int m0 = m0base + ch * SCHUNK;
        __syncthreads();
#pragma unroll
        for (int i = 0; i < 8; ++i) {
            int idx = t + i * 256;
            int r = idx >> 6, n = idx & 63;
            size_t rowz = (size_t)(m0 + r) * NPROJ;
            bS[r][n] = zx[rowz + OFF_B + n];
            cS[r][n] = zx[rowz + OFF_C + n];
            xS[r][n] = xh[(size_t)(m0 + r) * D_INNER + xcol + n];
        }
        if (t < SCHUNK) aS[t] = abar[(m0 + t) * N_HEADS + hh];
        __syncthreads();

        for (int r = 0; r < SCHUNK; ++r) {
            float a = aS[r];
            float xd = xS[r][d_local];
            const float* bp = &bS[r][g * 16];
            const float* cp = &cS[r][g * 16];
            float acc0 = 0.f, acc1 = 0.f;
#pragma unroll
            for (int i = 0; i < 16; i += 2) {
                hst[i]     = fmaf(a, hst[i],     bp[i]     * xd);
                acc0       = fmaf(hst[i],     cp[i],     acc0);
                hst[i + 1] = fmaf(a, hst[i + 1], bp[i + 1] * xd);
                acc1       = fmaf(hst[i + 1], cp[i + 1], acc1);
            }
            float acc = acc0 + acc1;
            acc += __shfl_xor(acc, 1);
            acc += __shfl_xor(acc, 2);
            if (g == 0)
                yscan[(size_t)(m0 + r) * D_INNER + xcol + d_local] = acc;
        }
    }
}

// ---------------------------------------------------------------------------
// y = (yscan + D*xh) * silu(z); RMSNorm over D_INNER; in-place on yscan.
// one block per row, 256 threads x 8 channels.
// ---------------------------------------------------------------------------
__global__ __launch_bounds__(256) void gate_norm_kernel(const float* __restrict__ zx,
                                                        const float* __restrict__ xh,
                                                        const float* __restrict__ Dp,
                                                        const float* __restrict__ nw,
                                                        float* __restrict__ y) {
    const int m = blockIdx.x;
    const int t = threadIdx.x;
    const size_t rowz = (size_t)m * NPROJ;
    const size_t rowy = (size_t)m * D_INNER;

    float v[8];
    float ss = 0.f;
#pragma unroll
    for (int i = 0; i < 8; ++i) {
        int c = t + i * 256;
        float ys = fmaf(Dp[c >> 8], xh[rowy + c], y[rowy + c]);
        float z  = zx[rowz + OFF_Z + c];
        float gated = ys * (z / (1.f + expf(-z)));
        v[i] = gated;
        ss += gated * gated;
    }
#pragma unroll
    for (int off = 1; off < 64; off <<= 1) ss += __shfl_xor(ss, off);

    __shared__ float red[4];
    if ((t & 63) == 0) red[t >> 6] = ss;
    __syncthreads();
    float tot = red[0] + red[1] + red[2] + red[3];
    float scale = 1.f / sqrtf(tot / (float)D_INNER + 1e-6f);

#pragma unroll
    for (int i = 0; i < 8; ++i) {
        int c = t + i * 256;
        y[rowy + c] = v[i] * scale * nw[c];
    }
}

// ---------------------------------------------------------------------------
extern "C" void kernel_launch(void* const* d_in, const int* in_sizes, int n_in,
                              void* d_out, int out_size, void* d_ws, size_t ws_size,
                              hipStream_t stream) {
    const float* x         = (const float*)d_in[0];
    const float* in_proj_w = (const float*)d_in[1];
    const float* conv_w    = (const float*)d_in[2];
    const float* conv_b    = (const float*)d_in[3];
    const float* A_log     = (const float*)d_in[4];
    const float* D_param   = (const float*)d_in[5];
    const float* dt_bias   = (const float*)d_in[6];
    const float* norm_w    = (const float*)d_in[7];
    const float* out_proj_w= (const float*)d_in[8];
    float* out = (float*)d_out;

    float* ws   = (float*)d_ws;
    float* zx   = ws;                                   // M_ROWS * NPROJ
    float* xh   = ws + (size_t)M_ROWS * NPROJ;          // M_ROWS * D_INNER
    float* ysc  = xh + (size_t)M_ROWS * D_INNER;        // M_ROWS * D_INNER
    float* ab   = ysc + (size_t)M_ROWS * D_INNER;       // M_ROWS * N_HEADS

    // 1) zxBCdt = x @ in_proj_w^T        (2048 x 4232, K=1024)
    dim3 g1((NPROJ + 127) / 128, M_ROWS / 128);
    gemm_abt<128, 128, 16><<<g1, 256, 0, stream>>>(x, in_proj_w, zx,
                                                   M_ROWS, NPROJ, DIM);

    // 2) conv + silu -> xh
    conv_silu_kernel<<<(M_ROWS * D_INNER) / 256, 256, 0, stream>>>(zx, conv_w, conv_b, xh);

    // 3) dt / a_bar
    dt_abar_kernel<<<(M_ROWS * N_HEADS) / 256, 256, 0, stream>>>(zx, dt_bias, A_log, ab);

    // 4) selective scan -> ysc
    scan_kernel<<<BATCH * N_HEADS * 4, 256, 0, stream>>>(zx, xh, ab, ysc);

    // 5) gate + rmsnorm (in-place on ysc)
    gate_norm_kernel<<<M_ROWS, 256, 0, stream>>>(zx, xh, D_param, norm_w, ysc);

    // 6) out = ysc @ out_proj_w^T       (2048 x 1024, K=2048)
    dim3 g2(DIM / 128, M_ROWS / 128);
    gemm_abt<128, 128, 16><<<g2, 256, 0, stream>>>(ysc, out_proj_w, out,
                                                   M_ROWS, DIM, D_INNER);
}

// Round 2
// 754.964 us; speedup vs baseline: 1.4032x; 1.4032x over previous
//
#include <hip/hip_runtime.h>
#include <hip/hip_bf16.h>
#include <math.h>

#define DIM      1024
#define D_STATE  64
#define D_CONV   4
#define N_HEADS  8
#define D_INNER  2048
#define HEAD_DIM 256
#define NPROJ    4232      // 2048 + 2048 + 8 + 64 + 64
#define BATCH    2
#define SEQ      1024
#define M_ROWS   (BATCH * SEQ)   // 2048
#define OFF_Z    0
#define OFF_XC   2048
#define OFF_DT   4096
#define OFF_B    4104
#define OFF_C    4168

#define CHUNK    64               // scan chunk length
#define N_CHUNK  (SEQ / CHUNK)    // 16
#define STATE_PER_BH (HEAD_DIM * D_STATE)   // 16384 floats

// ---------------------------------------------------------------------------
// fp32 tiled GEMM: C[M,N] = A[M,K] @ Bm[N,K]^T   (both operands K-contiguous)
// ---------------------------------------------------------------------------
template<int BM, int BN, int BK>
__global__ __launch_bounds__(256) void gemm_abt(const float* __restrict__ A,
                                                const float* __restrict__ Bm,
                                                float* __restrict__ C,
                                                int M, int N, int K) {
    __shared__ float As[BK][BM + 4];
    __shared__ float Bs[BK][BN + 4];

    const int tid = threadIdx.x;
    const int tx  = tid & 15;
    const int ty  = tid >> 4;
    const int m0  = blockIdx.y * BM;
    const int n0  = blockIdx.x * BN;

    float acc[8][8];
#pragma unroll
    for (int i = 0; i < 8; ++i)
#pragma unroll
        for (int j = 0; j < 8; ++j) acc[i][j] = 0.f;

    for (int k0 = 0; k0 < K; k0 += BK) {
#pragma unroll
        for (int f = tid; f < BM * (BK / 4); f += 256) {
            int row = f >> 2, c4 = f & 3;
            float4 v = *(const float4*)&A[(size_t)(m0 + row) * K + k0 + c4 * 4];
            As[c4 * 4 + 0][row] = v.x;
            As[c4 * 4 + 1][row] = v.y;
            As[c4 * 4 + 2][row] = v.z;
            As[c4 * 4 + 3][row] = v.w;
        }
#pragma unroll
        for (int f = tid; f < BN * (BK / 4); f += 256) {
            int row = f >> 2, c4 = f & 3;
            float4 v = make_float4(0.f, 0.f, 0.f, 0.f);
            if (n0 + row < N)
                v = *(const float4*)&Bm[(size_t)(n0 + row) * K + k0 + c4 * 4];
            Bs[c4 * 4 + 0][row] = v.x;
            Bs[c4 * 4 + 1][row] = v.y;
            Bs[c4 * 4 + 2][row] = v.z;
            Bs[c4 * 4 + 3][row] = v.w;
        }
        __syncthreads();
#pragma unroll
        for (int kk = 0; kk < BK; ++kk) {
            float a[8], b[8];
            float4 a0 = *(const float4*)&As[kk][ty * 8];
            float4 a1 = *(const float4*)&As[kk][ty * 8 + 4];
            float4 b0 = *(const float4*)&Bs[kk][tx * 8];
            float4 b1 = *(const float4*)&Bs[kk][tx * 8 + 4];
            a[0]=a0.x; a[1]=a0.y; a[2]=a0.z; a[3]=a0.w;
            a[4]=a1.x; a[5]=a1.y; a[6]=a1.z; a[7]=a1.w;
            b[0]=b0.x; b[1]=b0.y; b[2]=b0.z; b[3]=b0.w;
            b[4]=b1.x; b[5]=b1.y; b[6]=b1.z; b[7]=b1.w;
#pragma unroll
            for (int i = 0; i < 8; ++i)
#pragma unroll
                for (int j = 0; j < 8; ++j)
                    acc[i][j] = fmaf(a[i], b[j], acc[i][j]);
        }
        __syncthreads();
    }

    const int col0 = n0 + tx * 8;
#pragma unroll
    for (int i = 0; i < 8; ++i) {
        int row = m0 + ty * 8 + i;
        if (col0 < N) {
            *(float4*)&C[(size_t)row * N + col0]     = make_float4(acc[i][0], acc[i][1], acc[i][2], acc[i][3]);
            *(float4*)&C[(size_t)row * N + col0 + 4] = make_float4(acc[i][4], acc[i][5], acc[i][6], acc[i][7]);
        }
    }
}

// ---------------------------------------------------------------------------
// depthwise causal conv (k=4) + SiLU over the xc slice -> xh
// ---------------------------------------------------------------------------
__global__ __launch_bounds__(256) void conv_silu_kernel(const float* __restrict__ zx,
                                                        const float* __restrict__ conv_w,
                                                        const float* __restrict__ conv_b,
                                                        float* __restrict__ xh) {
    int idx = blockIdx.x * 256 + threadIdx.x;
    int c = idx & (D_INNER - 1);
    int m = idx >> 11;
    int l = m & (SEQ - 1);
    float acc = conv_b[c];
#pragma unroll
    for (int k = 0; k < D_CONV; ++k) {
        int lj = l + k - (D_CONV - 1);
        if (lj >= 0)
            acc = fmaf(zx[(size_t)(m + k - (D_CONV - 1)) * NPROJ + OFF_XC + c],
                       conv_w[c * D_CONV + k], acc);
    }
    xh[idx] = acc / (1.f + expf(-acc));
}

// ---------------------------------------------------------------------------
// dt = softplus(logits + dt_bias); a_bar = exp(dt * -exp(A_log))
// ---------------------------------------------------------------------------
__global__ __launch_bounds__(256) void dt_abar_kernel(const float* __restrict__ zx,
                                                      const float* __restrict__ dt_bias,
                                                      const float* __restrict__ A_log,
                                                      float* __restrict__ abar) {
    int idx = blockIdx.x * 256 + threadIdx.x;
    int h = idx & (N_HEADS - 1);
    int m = idx >> 3;
    float v = zx[(size_t)m * NPROJ + OFF_DT + h] + dt_bias[h];
    float dt = (v > 20.f) ? v : log1pf(expf(v));
    abar[idx] = expf(dt * -expf(A_log[h]));
}

// ---------------------------------------------------------------------------
// PASS 1: local scan within a 64-step chunk (zero initial state).
// block = (b, h, chunk, dq). Writes y_local and the chunk's final state.
// ---------------------------------------------------------------------------
#define SCHUNK 32
__global__ __launch_bounds__(256) void scan_local_kernel(const float* __restrict__ zx,
                                                         const float* __restrict__ xh,
                                                         const float* __restrict__ abar,
                                                         float* __restrict__ yscan,
                                                         float* __restrict__ Sloc) {
    const int blk = blockIdx.x;          // 0..1023
    const int dq = blk & 3;
    const int c  = (blk >> 2) & (N_CHUNK - 1);
    const int bh = blk >> 6;
    const int hh = bh & (N_HEADS - 1);
    const int b  = bh >> 3;
    const int t  = threadIdx.x;
    const int d_local = t >> 2;
    const int g = t & 3;

    __shared__ float aS[SCHUNK];
    __shared__ float bS[SCHUNK][D_STATE];
    __shared__ float cS[SCHUNK][D_STATE];
    __shared__ float xS[SCHUNK][64];

    float hst[16];
#pragma unroll
    for (int i = 0; i < 16; ++i) hst[i] = 0.f;

    const int m0base = b * SEQ + c * CHUNK;
    const int xcol = hh * HEAD_DIM + dq * 64;

    for (int st = 0; st < CHUNK / SCHUNK; ++st) {
        const int m0 = m0base + st * SCHUNK;
        __syncthreads();
#pragma unroll
        for (int i = 0; i < 8; ++i) {
            int idx = t + i * 256;
            int r = idx >> 6, n = idx & 63;
            size_t rowz = (size_t)(m0 + r) * NPROJ;
            bS[r][n] = zx[rowz + OFF_B + n];
            cS[r][n] = zx[rowz + OFF_C + n];
            xS[r][n] = xh[(size_t)(m0 + r) * D_INNER + xcol + n];
        }
        if (t < SCHUNK) aS[t] = abar[(m0 + t) * N_HEADS + hh];
        __syncthreads();

        for (int r = 0; r < SCHUNK; ++r) {
            float a = aS[r];
            float xd = xS[r][d_local];
            const float* bp = &bS[r][g * 16];
            const float* cp = &cS[r][g * 16];
            float acc0 = 0.f, acc1 = 0.f;
#pragma unroll
            for (int i = 0; i < 16; i += 2) {
                hst[i]     = fmaf(a, hst[i],     bp[i]     * xd);
                acc0       = fmaf(hst[i],     cp[i],     acc0);
                hst[i + 1] = fmaf(a, hst[i + 1], bp[i + 1] * xd);
                acc1       = fmaf(hst[i + 1], cp[i + 1], acc1);
            }
            float acc = acc0 + acc1;
            acc += __shfl_xor(acc, 1);
            acc += __shfl_xor(acc, 2);
            if (g == 0)
                yscan[(size_t)(m0 + r) * D_INNER + xcol + d_local] = acc;
        }
    }

    // store final local state S_c[d][n]
    size_t sbase = ((size_t)(bh * N_CHUNK + c) * HEAD_DIM + dq * 64 + d_local) * D_STATE + g * 16;
#pragma unroll
    for (int i = 0; i < 16; i += 4)
        *(float4*)&Sloc[sbase + i] = make_float4(hst[i], hst[i+1], hst[i+2], hst[i+3]);
}

// ---------------------------------------------------------------------------
// PASS 2: inter-chunk recurrence, in place on Sloc.
// After this kernel Sloc[bh][c] holds H_init(c) (the state ENTERING chunk c).
// block = (bh, ds) : 16 x 16 = 256 blocks; thread owns 4 state elements.
// ---------------------------------------------------------------------------
__global__ __launch_bounds__(256) void scan_combine_kernel(const float* __restrict__ abar,
                                                           float* __restrict__ Sloc) {
    const int blk = blockIdx.x;
    const int ds = blk & 15;
    const int bh = blk >> 4;
    const int hh = bh & (N_HEADS - 1);
    const int b  = bh >> 3;
    const int t  = threadIdx.x;

    __shared__ float PS[N_CHUNK];
    if (t < N_CHUNK) {
        float p = 1.f;
        int mbase = b * SEQ + t * CHUNK;
        for (int j = 0; j < CHUNK; ++j)
            p *= abar[(mbase + j) * N_HEADS + hh];
        PS[t] = p;
    }
    __syncthreads();

    float H[4] = {0.f, 0.f, 0.f, 0.f};
    for (int c = 0; c < N_CHUNK; ++c) {
        size_t base = (size_t)(bh * N_CHUNK + c) * STATE_PER_BH + ds * 1024 + t;
        float Sv[4];
#pragma unroll
        for (int i = 0; i < 4; ++i) Sv[i] = Sloc[base + i * 256];
#pragma unroll
        for (int i = 0; i < 4; ++i) Sloc[base + i * 256] = H[i];
        float P = PS[c];
#pragma unroll
        for (int i = 0; i < 4; ++i) H[i] = fmaf(P, H[i], Sv[i]);
    }
}

// ---------------------------------------------------------------------------
// PASS 3: y_t += cumA(t) * (C_t . H_init(chunk)).
// block = (b, h, chunk, dq); same thread layout as pass 1.
// ---------------------------------------------------------------------------
__global__ __launch_bounds__(256) void scan_correct_kernel(const float* __restrict__ zx,
                                                           const float* __restrict__ abar,
                                                           const float* __restrict__ Hini,
                                                           float* __restrict__ yscan) {
    const int blk = blockIdx.x;
    const int dq = blk & 3;
    const int c  = (blk >> 2) & (N_CHUNK - 1);
    const int bh = blk >> 6;
    const int hh = bh & (N_HEADS - 1);
    const int b  = bh >> 3;
    const int t  = threadIdx.x;
    const int d_local = t >> 2;
    const int g = t & 3;

    __shared__ float cS[CHUNK][D_STATE];
    __shared__ float aS[CHUNK];

    const int m0 = b * SEQ + c * CHUNK;
#pragma unroll
    for (int i = 0; i < 16; ++i) {
        int idx = t + i * 256;
        int r = idx >> 6, n = idx & 63;
        cS[r][n] = zx[(size_t)(m0 + r) * NPROJ + OFF_C + n];
    }
    if (t < CHUNK) aS[t] = abar[(m0 + t) * N_HEADS + hh];

    float H[16];
    size_t hbase = ((size_t)(bh * N_CHUNK + c) * HEAD_DIM + dq * 64 + d_local) * D_STATE + g * 16;
#pragma unroll
    for (int i = 0; i < 16; i += 4) {
        float4 v = *(const float4*)&Hini[hbase + i];
        H[i] = v.x; H[i+1] = v.y; H[i+2] = v.z; H[i+3] = v.w;
    }
    __syncthreads();

    const int xcol = hh * HEAD_DIM + dq * 64;
    float cum = 1.f;
    for (int r = 0; r < CHUNK; ++r) {
        cum *= aS[r];
        const float* cp = &cS[r][g * 16];
        float acc0 = 0.f, acc1 = 0.f;
#pragma unroll
        for (int i = 0; i < 16; i += 2) {
            acc0 = fmaf(H[i],     cp[i],     acc0);
            acc1 = fmaf(H[i + 1], cp[i + 1], acc1);
        }
        float acc = acc0 + acc1;
        acc += __shfl_xor(acc, 1);
        acc += __shfl_xor(acc, 2);
        if (g == 0)
            yscan[(size_t)(m0 + r) * D_INNER + xcol + d_local] += cum * acc;
    }
}

// ---------------------------------------------------------------------------
// y = (yscan + D*xh) * silu(z); RMSNorm over D_INNER; in-place on yscan.
// ---------------------------------------------------------------------------
__global__ __launch_bounds__(256) void gate_norm_kernel(const float* __restrict__ zx,
                                                        const float* __restrict__ xh,
                                                        const float* __restrict__ Dp,
                                                        const float* __restrict__ nw,
                                                        float* __restrict__ y) {
    const int m = blockIdx.x;
    const int t = threadIdx.x;
    const size_t rowz = (size_t)m * NPROJ;
    const size_t rowy = (size_t)m * D_INNER;

    float v[8];
    float ss = 0.f;
#pragma unroll
    for (int i = 0; i < 8; ++i) {
        int c = t + i * 256;
        float ys = fmaf(Dp[c >> 8], xh[rowy + c], y[rowy + c]);
        float z  = zx[rowz + OFF_Z + c];
        float gated = ys * (z / (1.f + expf(-z)));
        v[i] = gated;
        ss += gated * gated;
    }
#pragma unroll
    for (int off = 1; off < 64; off <<= 1) ss += __shfl_xor(ss, off);

    __shared__ float red[4];
    if ((t & 63) == 0) red[t >> 6] = ss;
    __syncthreads();
    float tot = red[0] + red[1] + red[2] + red[3];
    float scale = 1.f / sqrtf(tot / (float)D_INNER + 1e-6f);

#pragma unroll
    for (int i = 0; i < 8; ++i) {
        int c = t + i * 256;
        y[rowy + c] = v[i] * scale * nw[c];
    }
}

// ---------------------------------------------------------------------------
extern "C" void kernel_launch(void* const* d_in, const int* in_sizes, int n_in,
                              void* d_out, int out_size, void* d_ws, size_t ws_size,
                              hipStream_t stream) {
    const float* x         = (const float*)d_in[0];
    const float* in_proj_w = (const float*)d_in[1];
    const float* conv_w    = (const float*)d_in[2];
    const float* conv_b    = (const float*)d_in[3];
    const float* A_log     = (const float*)d_in[4];
    const float* D_param   = (const float*)d_in[5];
    const float* dt_bias   = (const float*)d_in[6];
    const float* norm_w    = (const float*)d_in[7];
    const float* out_proj_w= (const float*)d_in[8];
    float* out = (float*)d_out;

    float* ws   = (float*)d_ws;
    float* zx   = ws;                                   // M_ROWS * NPROJ
    float* xh   = zx  + (size_t)M_ROWS * NPROJ;         // M_ROWS * D_INNER
    float* ysc  = xh  + (size_t)M_ROWS * D_INNER;       // M_ROWS * D_INNER
    float* ab   = ysc + (size_t)M_ROWS * D_INNER;       // M_ROWS * N_HEADS
    float* Sloc = ab  + (size_t)M_ROWS * N_HEADS;       // 16 * 16 * 16384 floats (16 MB)

    // 1) zxBCdt = x @ in_proj_w^T        (2048 x 4232, K=1024)
    dim3 g1((NPROJ + 127) / 128, M_ROWS / 128);
    gemm_abt<128, 128, 16><<<g1, 256, 0, stream>>>(x, in_proj_w, zx,
                                                   M_ROWS, NPROJ, DIM);

    // 2) conv + silu -> xh
    conv_silu_kernel<<<(M_ROWS * D_INNER) / 256, 256, 0, stream>>>(zx, conv_w, conv_b, xh);

    // 3) dt / a_bar
    dt_abar_kernel<<<(M_ROWS * N_HEADS) / 256, 256, 0, stream>>>(zx, dt_bias, A_log, ab);

    // 4) chunk-parallel scan
    scan_local_kernel<<<BATCH * N_HEADS * N_CHUNK * 4, 256, 0, stream>>>(zx, xh, ab, ysc, Sloc);
    scan_combine_kernel<<<BATCH * N_HEADS * 16, 256, 0, stream>>>(ab, Sloc);
    scan_correct_kernel<<<BATCH * N_HEADS * N_CHUNK * 4, 256, 0, stream>>>(zx, ab, Sloc, ysc);

    // 5) gate + rmsnorm (in-place on ysc)
    gate_norm_kernel<<<M_ROWS, 256, 0, stream>>>(zx, xh, D_param, norm_w, ysc);

    // 6) out = ysc @ out_proj_w^T       (2048 x 1024, K=2048)
    dim3 g2(DIM / 128, M_ROWS / 128);
    gemm_abt<128, 128, 16><<<g2, 256, 0, stream>>>(ysc, out_proj_w, out,
                                                   M_ROWS, DIM, D_INNER);
}

// Round 4
// 346.412 us; speedup vs baseline: 3.0581x; 2.1794x over previous
//
#include <hip/hip_runtime.h>
#include <hip/hip_bf16.h>
#include <math.h>

#define DIM      1024
#define D_STATE  64
#define D_CONV   4
#define N_HEADS  8
#define D_INNER  2048
#define HEAD_DIM 256
#define NPROJ    4232      // 2048 + 2048 + 8 + 64 + 64
#define BATCH    2
#define SEQ      1024
#define M_ROWS   (BATCH * SEQ)   // 2048
#define OFF_Z    0
#define OFF_XC   2048
#define OFF_DT   4096
#define OFF_B    4104
#define OFF_C    4168

#define CHUNK    64
#define N_CHUNK  (SEQ / CHUNK)    // 16
#define STATE_PER_BH (HEAD_DIM * D_STATE)   // 16384 floats

#define NPROJ_PAD 4352            // 34 * 128 (GEMM1 N padded to tile)

typedef unsigned short u16;
typedef __bf16 bf16x8 __attribute__((ext_vector_type(8)));
typedef float  f32x4  __attribute__((ext_vector_type(4)));

__device__ __forceinline__ u16 f2bf(float f) {
    unsigned int u = __float_as_uint(f);
    unsigned int r = (u + 0x7FFFu + ((u >> 16) & 1u)) >> 16;   // RNE
    return (u16)r;
}
__device__ __forceinline__ float bf2f(u16 h) {
    return __uint_as_float(((unsigned int)h) << 16);
}

__device__ __forceinline__ void load_lds16(const void* g, void* l) {
    __builtin_amdgcn_global_load_lds((const __attribute__((address_space(1))) unsigned int*)g,
                                     (__attribute__((address_space(3))) unsigned int*)l,
                                     16, 0, 0);
}

// ---------------------------------------------------------------------------
// fp32 -> (bf16 hi, bf16 lo) split cast with zero tail padding.
// hi = RNE(v), lo = RNE(v - hi): 3-term MFMA gives ~fp32 GEMM accuracy.
// ---------------------------------------------------------------------------
__global__ __launch_bounds__(256) void cast_split_kernel(const float* __restrict__ src,
                                                         u16* __restrict__ hi,
                                                         u16* __restrict__ lo,
                                                         int n_src, int n_total) {
    int i4 = (blockIdx.x * 256 + threadIdx.x) * 4;
    if (i4 >= n_total) return;
    ushort4 h, l;
    if (i4 < n_src) {
        float4 v = *(const float4*)&src[i4];
        h.x = f2bf(v.x); h.y = f2bf(v.y); h.z = f2bf(v.z); h.w = f2bf(v.w);
        l.x = f2bf(v.x - bf2f(h.x));
        l.y = f2bf(v.y - bf2f(h.y));
        l.z = f2bf(v.z - bf2f(h.z));
        l.w = f2bf(v.w - bf2f(h.w));
    } else {
        h.x = h.y = h.z = h.w = 0;
        l.x = l.y = l.z = l.w = 0;
    }
    *(ushort4*)&hi[i4] = h;
    *(ushort4*)&lo[i4] = l;
}

// ---------------------------------------------------------------------------
// split-bf16 MFMA GEMM: C = A @ B^T with A ~ Ah+Al, B ~ Bh+Bl (fp32 accum).
// acc += Ah*Bh + Al*Bh + Ah*Bl  (Al*Bl ~ 2^-18, dropped).
// 128 x BN tile, BK=32, 256 threads, 16x16x32 mfma, global_load_lds staging,
// XOR chunk swizzle (2-way aliasing only — free per m136).
// ---------------------------------------------------------------------------
template<int BN>
__global__ __launch_bounds__(256) void gemm_mfma3(const u16* __restrict__ Ah,
                                                  const u16* __restrict__ Al,
                                                  const u16* __restrict__ Bh,
                                                  const u16* __restrict__ Bl,
                                                  float* __restrict__ C,
                                                  int K, int ldc, int Nstore) {
    __shared__ u16 AsH[128 * 32];
    __shared__ u16 AsL[128 * 32];
    __shared__ u16 BsH[BN * 32];
    __shared__ u16 BsL[BN * 32];

    const int tid  = threadIdx.x;
    const int wave = tid >> 6;
    const int lane = tid & 63;
    const int fr   = lane & 15;
    const int kc   = lane >> 4;
    const int m0   = blockIdx.y * 128;
    const int n0   = blockIdx.x * BN;
    const int wm   = (wave & 1) * 64;
    const int wn   = (wave >> 1) * (BN / 2);

    f32x4 acc[4][BN / 32];
#pragma unroll
    for (int i = 0; i < 4; ++i)
#pragma unroll
        for (int j = 0; j < BN / 32; ++j) acc[i][j] = (f32x4)0.f;

    for (int k0 = 0; k0 < K; k0 += 32) {
        __syncthreads();
        // stage A hi/lo tiles: 512 chunks of 16B each, 2/thread each
#pragma unroll
        for (int q = 0; q < 2; ++q) {
            int s = wave * 128 + q * 64 + lane;
            int r = s >> 2, pc = s & 3;
            int gc = pc ^ ((r >> 1) & 3);
            size_t goff = (size_t)(m0 + r) * K + k0 + gc * 8;
            load_lds16(Ah + goff, &AsH[(wave * 128 + q * 64) * 8]);
            load_lds16(Al + goff, &AsL[(wave * 128 + q * 64) * 8]);
        }
        // stage B hi/lo tiles: BN*4 chunks each
#pragma unroll
        for (int q = 0; q < BN / 64; ++q) {
            int s = wave * BN + q * 64 + lane;
            int r = s >> 2, pc = s & 3;
            int gc = pc ^ ((r >> 1) & 3);
            size_t goff = (size_t)(n0 + r) * K + k0 + gc * 8;
            load_lds16(Bh + goff, &BsH[(wave * BN + q * 64) * 8]);
            load_lds16(Bl + goff, &BsL[(wave * BN + q * 64) * 8]);
        }
        __syncthreads();

        bf16x8 afh[4], afl[4];
#pragma unroll
        for (int i = 0; i < 4; ++i) {
            int r = wm + i * 16 + fr;
            int off = r * 32 + (kc ^ ((r >> 1) & 3)) * 8;
            afh[i] = *(const bf16x8*)&AsH[off];
            afl[i] = *(const bf16x8*)&AsL[off];
        }
        bf16x8 bfh[BN / 32], bfl[BN / 32];
#pragma unroll
        for (int j = 0; j < BN / 32; ++j) {
            int r = wn + j * 16 + fr;
            int off = r * 32 + (kc ^ ((r >> 1) & 3)) * 8;
            bfh[j] = *(const bf16x8*)&BsH[off];
            bfl[j] = *(const bf16x8*)&BsL[off];
        }
#pragma unroll
        for (int i = 0; i < 4; ++i)
#pragma unroll
            for (int j = 0; j < BN / 32; ++j) {
                acc[i][j] = __builtin_amdgcn_mfma_f32_16x16x32_bf16(afh[i], bfh[j], acc[i][j], 0, 0, 0);
                acc[i][j] = __builtin_amdgcn_mfma_f32_16x16x32_bf16(afl[i], bfh[j], acc[i][j], 0, 0, 0);
                acc[i][j] = __builtin_amdgcn_mfma_f32_16x16x32_bf16(afh[i], bfl[j], acc[i][j], 0, 0, 0);
            }
    }

    // epilogue: C/D layout col=lane&15, row=(lane>>4)*4+reg  [m89/m91]
    const int row0 = m0 + wm + (lane >> 4) * 4;
    const int colb = n0 + wn + fr;
#pragma unroll
    for (int i = 0; i < 4; ++i)
#pragma unroll
        for (int j = 0; j < BN / 32; ++j) {
            int col = colb + j * 16;
            if (col < Nstore) {
#pragma unroll
                for (int t = 0; t < 4; ++t)
                    C[(size_t)(row0 + i * 16 + t) * ldc + col] = acc[i][j][t];
            }
        }
}

// ---------------------------------------------------------------------------
// depthwise causal conv (k=4) + SiLU over the xc slice -> xh
// ---------------------------------------------------------------------------
__global__ __launch_bounds__(256) void conv_silu_kernel(const float* __restrict__ zx,
                                                        const float* __restrict__ conv_w,
                                                        const float* __restrict__ conv_b,
                                                        float* __restrict__ xh) {
    int idx = blockIdx.x * 256 + threadIdx.x;
    int c = idx & (D_INNER - 1);
    int m = idx >> 11;
    int l = m & (SEQ - 1);
    float acc = conv_b[c];
#pragma unroll
    for (int k = 0; k < D_CONV; ++k) {
        int lj = l + k - (D_CONV - 1);
        if (lj >= 0)
            acc = fmaf(zx[(size_t)(m + k - (D_CONV - 1)) * NPROJ + OFF_XC + c],
                       conv_w[c * D_CONV + k], acc);
    }
    xh[idx] = acc / (1.f + expf(-acc));
}

// ---------------------------------------------------------------------------
// dt = softplus(logits + dt_bias); a_bar = exp(dt * -exp(A_log))
// ---------------------------------------------------------------------------
__global__ __launch_bounds__(256) void dt_abar_kernel(const float* __restrict__ zx,
                                                      const float* __restrict__ dt_bias,
                                                      const float* __restrict__ A_log,
                                                      float* __restrict__ abar) {
    int idx = blockIdx.x * 256 + threadIdx.x;
    int h = idx & (N_HEADS - 1);
    int m = idx >> 3;
    float v = zx[(size_t)m * NPROJ + OFF_DT + h] + dt_bias[h];
    float dt = (v > 20.f) ? v : log1pf(expf(v));
    abar[idx] = expf(dt * -expf(A_log[h]));
}

// ---------------------------------------------------------------------------
// PASS 1: local scan within a 64-step chunk (zero initial state).
// ---------------------------------------------------------------------------
#define SCHUNK 32
__global__ __launch_bounds__(256) void scan_local_kernel(const float* __restrict__ zx,
                                                         const float* __restrict__ xh,
                                                         const float* __restrict__ abar,
                                                         float* __restrict__ yscan,
                                                         float* __restrict__ Sloc) {
    const int blk = blockIdx.x;          // 0..1023
    const int dq = blk & 3;
    const int c  = (blk >> 2) & (N_CHUNK - 1);
    const int bh = blk >> 6;
    const int hh = bh & (N_HEADS - 1);
    const int b  = bh >> 3;
    const int t  = threadIdx.x;
    const int d_local = t >> 2;
    const int g = t & 3;

    __shared__ float aS[SCHUNK];
    __shared__ float bS[SCHUNK][D_STATE];
    __shared__ float cS[SCHUNK][D_STATE];
    __shared__ float xS[SCHUNK][64];

    float hst[16];
#pragma unroll
    for (int i = 0; i < 16; ++i) hst[i] = 0.f;

    const int m0base = b * SEQ + c * CHUNK;
    const int xcol = hh * HEAD_DIM + dq * 64;

    for (int st = 0; st < CHUNK / SCHUNK; ++st) {
        const int m0 = m0base + st * SCHUNK;
        __syncthreads();
#pragma unroll
        for (int i = 0; i < 8; ++i) {
            int idx = t + i * 256;
            int r = idx >> 6, n = idx & 63;
            size_t rowz = (size_t)(m0 + r) * NPROJ;
            bS[r][n] = zx[rowz + OFF_B + n];
            cS[r][n] = zx[rowz + OFF_C + n];
            xS[r][n] = xh[(size_t)(m0 + r) * D_INNER + xcol + n];
        }
        if (t < SCHUNK) aS[t] = abar[(m0 + t) * N_HEADS + hh];
        __syncthreads();

        for (int r = 0; r < SCHUNK; ++r) {
            float a = aS[r];
            float xd = xS[r][d_local];
            const float* bp = &bS[r][g * 16];
            const float* cp = &cS[r][g * 16];
            float acc0 = 0.f, acc1 = 0.f;
#pragma unroll
            for (int i = 0; i < 16; i += 2) {
                hst[i]     = fmaf(a, hst[i],     bp[i]     * xd);
                acc0       = fmaf(hst[i],     cp[i],     acc0);
                hst[i + 1] = fmaf(a, hst[i + 1], bp[i + 1] * xd);
                acc1       = fmaf(hst[i + 1], cp[i + 1], acc1);
            }
            float acc = acc0 + acc1;
            acc += __shfl_xor(acc, 1);
            acc += __shfl_xor(acc, 2);
            if (g == 0)
                yscan[(size_t)(m0 + r) * D_INNER + xcol + d_local] = acc;
        }
    }

    size_t sbase = ((size_t)(bh * N_CHUNK + c) * HEAD_DIM + dq * 64 + d_local) * D_STATE + g * 16;
#pragma unroll
    for (int i = 0; i < 16; i += 4)
        *(float4*)&Sloc[sbase + i] = make_float4(hst[i], hst[i+1], hst[i+2], hst[i+3]);
}

// ---------------------------------------------------------------------------
// PASS 2: inter-chunk recurrence in place on Sloc -> H_init(c).
// ---------------------------------------------------------------------------
__global__ __launch_bounds__(256) void scan_combine_kernel(const float* __restrict__ abar,
                                                           float* __restrict__ Sloc) {
    const int blk = blockIdx.x;
    const int ds = blk & 15;
    const int bh = blk >> 4;
    const int hh = bh & (N_HEADS - 1);
    const int b  = bh >> 3;
    const int t  = threadIdx.x;

    __shared__ float PS[N_CHUNK];
    if (t < N_CHUNK) {
        float p = 1.f;
        int mbase = b * SEQ + t * CHUNK;
        for (int j = 0; j < CHUNK; ++j)
            p *= abar[(mbase + j) * N_HEADS + hh];
        PS[t] = p;
    }
    __syncthreads();

    float H[4] = {0.f, 0.f, 0.f, 0.f};
    for (int c = 0; c < N_CHUNK; ++c) {
        size_t base = (size_t)(bh * N_CHUNK + c) * STATE_PER_BH + ds * 1024 + t;
        float Sv[4];
#pragma unroll
        for (int i = 0; i < 4; ++i) Sv[i] = Sloc[base + i * 256];
#pragma unroll
        for (int i = 0; i < 4; ++i) Sloc[base + i * 256] = H[i];
        float P = PS[c];
#pragma unroll
        for (int i = 0; i < 4; ++i) H[i] = fmaf(P, H[i], Sv[i]);
    }
}

// ---------------------------------------------------------------------------
// PASS 3: y_t += cumA(t) * (C_t . H_init(chunk)).
// ---------------------------------------------------------------------------
__global__ __launch_bounds__(256) void scan_correct_kernel(const float* __restrict__ zx,
                                                           const float* __restrict__ abar,
                                                           const float* __restrict__ Hini,
                                                           float* __restrict__ yscan) {
    const int blk = blockIdx.x;
    const int dq = blk & 3;
    const int c  = (blk >> 2) & (N_CHUNK - 1);
    const int bh = blk >> 6;
    const int hh = bh & (N_HEADS - 1);
    const int b  = bh >> 3;
    const int t  = threadIdx.x;
    const int d_local = t >> 2;
    const int g = t & 3;

    __shared__ float cS[CHUNK][D_STATE];
    __shared__ float aS[CHUNK];

    const int m0 = b * SEQ + c * CHUNK;
#pragma unroll
    for (int i = 0; i < 16; ++i) {
        int idx = t + i * 256;
        int r = idx >> 6, n = idx & 63;
        cS[r][n] = zx[(size_t)(m0 + r) * NPROJ + OFF_C + n];
    }
    if (t < CHUNK) aS[t] = abar[(m0 + t) * N_HEADS + hh];

    float H[16];
    size_t hbase = ((size_t)(bh * N_CHUNK + c) * HEAD_DIM + dq * 64 + d_local) * D_STATE + g * 16;
#pragma unroll
    for (int i = 0; i < 16; i += 4) {
        float4 v = *(const float4*)&Hini[hbase + i];
        H[i] = v.x; H[i+1] = v.y; H[i+2] = v.z; H[i+3] = v.w;
    }
    __syncthreads();

    const int xcol = hh * HEAD_DIM + dq * 64;
    float cum = 1.f;
    for (int r = 0; r < CHUNK; ++r) {
        cum *= aS[r];
        const float* cp = &cS[r][g * 16];
        float acc0 = 0.f, acc1 = 0.f;
#pragma unroll
        for (int i = 0; i < 16; i += 2) {
            acc0 = fmaf(H[i],     cp[i],     acc0);
            acc1 = fmaf(H[i + 1], cp[i + 1], acc1);
        }
        float acc = acc0 + acc1;
        acc += __shfl_xor(acc, 1);
        acc += __shfl_xor(acc, 2);
        if (g == 0)
            yscan[(size_t)(m0 + r) * D_INNER + xcol + d_local] += cum * acc;
    }
}

// ---------------------------------------------------------------------------
// y = (yscan + D*xh) * silu(z); RMSNorm over D_INNER; fp32 in-place on ysc.
// (row-local writes only -> no cross-block aliasing)
// ---------------------------------------------------------------------------
__global__ __launch_bounds__(256) void gate_norm_kernel(const float* __restrict__ zx,
                                                        const float* __restrict__ xh,
                                                        const float* __restrict__ Dp,
                                                        const float* __restrict__ nw,
                                                        float* __restrict__ y) {
    const int m = blockIdx.x;
    const int t = threadIdx.x;
    const size_t rowz = (size_t)m * NPROJ;
    const size_t rowy = (size_t)m * D_INNER;

    float v[8];
    float ss = 0.f;
#pragma unroll
    for (int i = 0; i < 8; ++i) {
        int c = t + i * 256;
        float ys = fmaf(Dp[c >> 8], xh[rowy + c], y[rowy + c]);
        float z  = zx[rowz + OFF_Z + c];
        float gated = ys * (z / (1.f + expf(-z)));
        v[i] = gated;
        ss += gated * gated;
    }
#pragma unroll
    for (int off = 1; off < 64; off <<= 1) ss += __shfl_xor(ss, off);

    __shared__ float red[4];
    if ((t & 63) == 0) red[t >> 6] = ss;
    __syncthreads();
    float tot = red[0] + red[1] + red[2] + red[3];
    float scale = 1.f / sqrtf(tot / (float)D_INNER + 1e-6f);

#pragma unroll
    for (int i = 0; i < 8; ++i) {
        int c = t + i * 256;
        y[rowy + c] = v[i] * scale * nw[c];
    }
}

// ---------------------------------------------------------------------------
extern "C" void kernel_launch(void* const* d_in, const int* in_sizes, int n_in,
                              void* d_out, int out_size, void* d_ws, size_t ws_size,
                              hipStream_t stream) {
    const float* x         = (const float*)d_in[0];
    const float* in_proj_w = (const float*)d_in[1];
    const float* conv_w    = (const float*)d_in[2];
    const float* conv_b    = (const float*)d_in[3];
    const float* A_log     = (const float*)d_in[4];
    const float* D_param   = (const float*)d_in[5];
    const float* dt_bias   = (const float*)d_in[6];
    const float* norm_w    = (const float*)d_in[7];
    const float* out_proj_w= (const float*)d_in[8];
    float* out = (float*)d_out;

    float* ws   = (float*)d_ws;
    float* zx   = ws;                                   // M_ROWS * NPROJ fp32   (34.7 MB)
    float* xh   = zx  + (size_t)M_ROWS * NPROJ;         // M_ROWS * D_INNER fp32 (16.8 MB)
    float* ysc  = xh  + (size_t)M_ROWS * D_INNER;       // M_ROWS * D_INNER fp32 (16.8 MB)
    float* ab   = ysc + (size_t)M_ROWS * D_INNER;       // M_ROWS * N_HEADS fp32
    float* Sloc = ab  + (size_t)M_ROWS * N_HEADS;       // 16*16*16384 fp32 (16.8 MB)

    // bf16 hi/lo overlays on regions that are DEAD at time of use:
    u16* xbf_h  = (u16*)ysc;                            // dead until scan pass1
    u16* xbf_l  = xbf_h + (size_t)M_ROWS * DIM;
    u16* wibf_h = (u16*)xh;                             // dead until conv (after GEMM1)
    u16* wibf_l = (u16*)Sloc;                           // dead until scan pass1
    u16* ybf_h  = (u16*)zx;                             // zx dead after gate_norm
    u16* ybf_l  = ybf_h + (size_t)M_ROWS * D_INNER;
    u16* wobf_h = (u16*)xh;                             // xh dead after gate_norm
    u16* wobf_l = wobf_h + (size_t)DIM * D_INNER;

    // split casts for GEMM1
    cast_split_kernel<<<(M_ROWS * DIM) / 1024, 256, 0, stream>>>(
        x, xbf_h, xbf_l, M_ROWS * DIM, M_ROWS * DIM);
    cast_split_kernel<<<(NPROJ_PAD * DIM) / 1024, 256, 0, stream>>>(
        in_proj_w, wibf_h, wibf_l, NPROJ * DIM, NPROJ_PAD * DIM);

    // 1) zxBCdt = x @ in_proj_w^T  (2048 x 4232, K=1024), split bf16 MFMA
    gemm_mfma3<128><<<dim3(NPROJ_PAD / 128, M_ROWS / 128), 256, 0, stream>>>(
        xbf_h, xbf_l, wibf_h, wibf_l, zx, DIM, NPROJ, NPROJ);

    // 2) conv + silu -> xh
    conv_silu_kernel<<<(M_ROWS * D_INNER) / 256, 256, 0, stream>>>(zx, conv_w, conv_b, xh);

    // 3) dt / a_bar
    dt_abar_kernel<<<(M_ROWS * N_HEADS) / 256, 256, 0, stream>>>(zx, dt_bias, A_log, ab);

    // 4) chunk-parallel scan
    scan_local_kernel<<<BATCH * N_HEADS * N_CHUNK * 4, 256, 0, stream>>>(zx, xh, ab, ysc, Sloc);
    scan_combine_kernel<<<BATCH * N_HEADS * 16, 256, 0, stream>>>(ab, Sloc);
    scan_correct_kernel<<<BATCH * N_HEADS * N_CHUNK * 4, 256, 0, stream>>>(zx, ab, Sloc, ysc);

    // 5) gate + rmsnorm (fp32, in-place on ysc)
    gate_norm_kernel<<<M_ROWS, 256, 0, stream>>>(zx, xh, D_param, norm_w, ysc);

    // split casts for GEMM2 (zx and xh are dead now)
    cast_split_kernel<<<(M_ROWS * D_INNER) / 1024, 256, 0, stream>>>(
        ysc, ybf_h, ybf_l, M_ROWS * D_INNER, M_ROWS * D_INNER);
    cast_split_kernel<<<(DIM * D_INNER) / 1024, 256, 0, stream>>>(
        out_proj_w, wobf_h, wobf_l, DIM * D_INNER, DIM * D_INNER);

    // 6) out = y @ out_proj_w^T  (2048 x 1024, K=2048), split bf16 MFMA
    gemm_mfma3<64><<<dim3(DIM / 64, M_ROWS / 128), 256, 0, stream>>>(
        ybf_h, ybf_l, wobf_h, wobf_l, out, D_INNER, DIM, DIM);
}

// Round 5
// 327.144 us; speedup vs baseline: 3.2382x; 1.0589x over previous
//
#include <hip/hip_runtime.h>
#include <hip/hip_bf16.h>
#include <math.h>

#define DIM      1024
#define D_STATE  64
#define D_CONV   4
#define N_HEADS  8
#define D_INNER  2048
#define HEAD_DIM 256
#define NPROJ    4232      // 2048 + 2048 + 8 + 64 + 64
#define BATCH    2
#define SEQ      1024
#define M_ROWS   (BATCH * SEQ)   // 2048
#define OFF_Z    0
#define OFF_XC   2048
#define OFF_DT   4096
#define OFF_B    4104
#define OFF_C    4168

#define CHUNK    64
#define N_CHUNK  (SEQ / CHUNK)    // 16
#define STATE_PER_BH (HEAD_DIM * D_STATE)   // 16384 floats

#define NPROJ_PAD 4352            // 34 * 128 (GEMM1 N padded to tile)

typedef unsigned short u16;
typedef __bf16 bf16x8 __attribute__((ext_vector_type(8)));
typedef float  f32x4  __attribute__((ext_vector_type(4)));

__device__ __forceinline__ u16 f2bf(float f) {
    unsigned int u = __float_as_uint(f);
    unsigned int r = (u + 0x7FFFu + ((u >> 16) & 1u)) >> 16;   // RNE
    return (u16)r;
}
__device__ __forceinline__ float bf2f(u16 h) {
    return __uint_as_float(((unsigned int)h) << 16);
}

__device__ __forceinline__ void load_lds16(const void* g, void* l) {
    __builtin_amdgcn_global_load_lds((const __attribute__((address_space(1))) unsigned int*)g,
                                     (__attribute__((address_space(3))) unsigned int*)l,
                                     16, 0, 0);
}

// ---------------------------------------------------------------------------
// fp32 -> (bf16 hi, bf16 lo) split cast with zero tail padding.
// ---------------------------------------------------------------------------
__global__ __launch_bounds__(256) void cast_split_kernel(const float* __restrict__ src,
                                                         u16* __restrict__ hi,
                                                         u16* __restrict__ lo,
                                                         int n_src, int n_total) {
    int i4 = (blockIdx.x * 256 + threadIdx.x) * 4;
    if (i4 >= n_total) return;
    ushort4 h, l;
    if (i4 < n_src) {
        float4 v = *(const float4*)&src[i4];
        h.x = f2bf(v.x); h.y = f2bf(v.y); h.z = f2bf(v.z); h.w = f2bf(v.w);
        l.x = f2bf(v.x - bf2f(h.x));
        l.y = f2bf(v.y - bf2f(h.y));
        l.z = f2bf(v.z - bf2f(h.z));
        l.w = f2bf(v.w - bf2f(h.w));
    } else {
        h.x = h.y = h.z = h.w = 0;
        l.x = l.y = l.z = l.w = 0;
    }
    *(ushort4*)&hi[i4] = h;
    *(ushort4*)&lo[i4] = l;
}

// ---------------------------------------------------------------------------
// split-bf16 MFMA GEMM: C = A @ B^T, A ~ Ah+Al, B ~ Bh+Bl, fp32 accum.
// acc += Ah*Bh + Al*Bh + Ah*Bl.
// BM=64 x BN tile, BK=32, 256 threads = 4 waves along N (WN = BN/4).
// Optional split-K via gridDim.z; partial c for slice z at C + z*zstride.
// ---------------------------------------------------------------------------
template<int BN>
__global__ __launch_bounds__(256) void gemm_mfma3(const u16* __restrict__ Ah,
                                                  const u16* __restrict__ Al,
                                                  const u16* __restrict__ Bh,
                                                  const u16* __restrict__ Bl,
                                                  float* __restrict__ C,
                                                  int K, int ldc, int Nstore,
                                                  size_t zstride) {
    __shared__ u16 AsH[64 * 32];
    __shared__ u16 AsL[64 * 32];
    __shared__ u16 BsH[BN * 32];
    __shared__ u16 BsL[BN * 32];

    const int tid  = threadIdx.x;
    const int wave = tid >> 6;
    const int lane = tid & 63;
    const int fr   = lane & 15;
    const int kc   = lane >> 4;
    const int m0   = blockIdx.y * 64;
    const int n0   = blockIdx.x * BN;
    const int wn   = wave * (BN / 4);

    const int kPer = K / gridDim.z;
    const int kBeg = blockIdx.z * kPer;
    C += (size_t)blockIdx.z * zstride;

    f32x4 acc[4][BN / 64];
#pragma unroll
    for (int i = 0; i < 4; ++i)
#pragma unroll
        for (int j = 0; j < BN / 64; ++j) acc[i][j] = (f32x4)0.f;

    for (int k0 = kBeg; k0 < kBeg + kPer; k0 += 32) {
        __syncthreads();
        // stage A hi/lo: 256 chunks of 16B each, 1/thread each
        {
            int s = wave * 64 + lane;
            int r = s >> 2, pc = s & 3;
            int gc = pc ^ ((r >> 1) & 3);
            size_t goff = (size_t)(m0 + r) * K + k0 + gc * 8;
            load_lds16(Ah + goff, &AsH[(wave * 64) * 8]);
            load_lds16(Al + goff, &AsL[(wave * 64) * 8]);
        }
        // stage B hi/lo: BN*4 chunks each
#pragma unroll
        for (int q = 0; q < BN / 64; ++q) {
            int s = (wave * (BN / 64) + q) * 64 + lane;
            int r = s >> 2, pc = s & 3;
            int gc = pc ^ ((r >> 1) & 3);
            size_t goff = (size_t)(n0 + r) * K + k0 + gc * 8;
            load_lds16(Bh + goff, &BsH[((wave * (BN / 64) + q) * 64) * 8]);
            load_lds16(Bl + goff, &BsL[((wave * (BN / 64) + q) * 64) * 8]);
        }
        __syncthreads();

        bf16x8 afh[4], afl[4];
#pragma unroll
        for (int i = 0; i < 4; ++i) {
            int r = i * 16 + fr;
            int off = r * 32 + (kc ^ ((r >> 1) & 3)) * 8;
            afh[i] = *(const bf16x8*)&AsH[off];
            afl[i] = *(const bf16x8*)&AsL[off];
        }
        bf16x8 bfh[BN / 64], bfl[BN / 64];
#pragma unroll
        for (int j = 0; j < BN / 64; ++j) {
            int r = wn + j * 16 + fr;
            int off = r * 32 + (kc ^ ((r >> 1) & 3)) * 8;
            bfh[j] = *(const bf16x8*)&BsH[off];
            bfl[j] = *(const bf16x8*)&BsL[off];
        }
#pragma unroll
        for (int i = 0; i < 4; ++i)
#pragma unroll
            for (int j = 0; j < BN / 64; ++j) {
                acc[i][j] = __builtin_amdgcn_mfma_f32_16x16x32_bf16(afh[i], bfh[j], acc[i][j], 0, 0, 0);
                acc[i][j] = __builtin_amdgcn_mfma_f32_16x16x32_bf16(afl[i], bfh[j], acc[i][j], 0, 0, 0);
                acc[i][j] = __builtin_amdgcn_mfma_f32_16x16x32_bf16(afh[i], bfl[j], acc[i][j], 0, 0, 0);
            }
    }

    // epilogue: C/D layout col=lane&15, row=(lane>>4)*4+reg  [m89/m91]
    const int row0 = m0 + (lane >> 4) * 4;
    const int colb = n0 + wn + fr;
#pragma unroll
    for (int i = 0; i < 4; ++i)
#pragma unroll
        for (int j = 0; j < BN / 64; ++j) {
            int col = colb + j * 16;
            if (col < Nstore) {
#pragma unroll
                for (int t = 0; t < 4; ++t)
                    C[(size_t)(row0 + i * 16 + t) * ldc + col] = acc[i][j][t];
            }
        }
}

// ---------------------------------------------------------------------------
// split-K=2 partial reduce: out = p[0..n) + p[n..2n)
// ---------------------------------------------------------------------------
__global__ __launch_bounds__(256) void reduce2_kernel(const float* __restrict__ p,
                                                      float* __restrict__ out, int n) {
    int i4 = (blockIdx.x * 256 + threadIdx.x) * 4;
    float4 a = *(const float4*)&p[i4];
    float4 b = *(const float4*)&p[(size_t)n + i4];
    *(float4*)&out[i4] = make_float4(a.x + b.x, a.y + b.y, a.z + b.z, a.w + b.w);
}

// ---------------------------------------------------------------------------
// depthwise causal conv (k=4) + SiLU -> xh; also (first 64 blocks) dt/a_bar.
// ---------------------------------------------------------------------------
__global__ __launch_bounds__(256) void conv_silu_kernel(const float* __restrict__ zx,
                                                        const float* __restrict__ conv_w,
                                                        const float* __restrict__ conv_b,
                                                        const float* __restrict__ dt_bias,
                                                        const float* __restrict__ A_log,
                                                        float* __restrict__ xh,
                                                        float* __restrict__ abar) {
    int idx = blockIdx.x * 256 + threadIdx.x;
    int c = idx & (D_INNER - 1);
    int m = idx >> 11;
    int l = m & (SEQ - 1);
    float acc = conv_b[c];
#pragma unroll
    for (int k = 0; k < D_CONV; ++k) {
        int lj = l + k - (D_CONV - 1);
        if (lj >= 0)
            acc = fmaf(zx[(size_t)(m + k - (D_CONV - 1)) * NPROJ + OFF_XC + c],
                       conv_w[c * D_CONV + k], acc);
    }
    xh[idx] = acc / (1.f + expf(-acc));

    if (blockIdx.x < (M_ROWS * N_HEADS) / 256) {
        int di = blockIdx.x * 256 + threadIdx.x;
        int h = di & (N_HEADS - 1);
        int dm = di >> 3;
        float v = zx[(size_t)dm * NPROJ + OFF_DT + h] + dt_bias[h];
        float dt = (v > 20.f) ? v : log1pf(expf(v));
        abar[di] = expf(dt * -expf(A_log[h]));
    }
}

// ---------------------------------------------------------------------------
// PASS 1: local scan within a 64-step chunk (zero initial state).
// ---------------------------------------------------------------------------
#define SCHUNK 32
__global__ __launch_bounds__(256) void scan_local_kernel(const float* __restrict__ zx,
                                                         const float* __restrict__ xh,
                                                         const float* __restrict__ abar,
                                                         float* __restrict__ yscan,
                                                         float* __restrict__ Sloc) {
    const int blk = blockIdx.x;          // 0..1023
    const int dq = blk & 3;
    const int c  = (blk >> 2) & (N_CHUNK - 1);
    const int bh = blk >> 6;
    const int hh = bh & (N_HEADS - 1);
    const int b  = bh >> 3;
    const int t  = threadIdx.x;
    const int d_local = t >> 2;
    const int g = t & 3;

    __shared__ float aS[SCHUNK];
    __shared__ float bS[SCHUNK][D_STATE];
    __shared__ float cS[SCHUNK][D_STATE];
    __shared__ float xS[SCHUNK][64];

    float hst[16];
#pragma unroll
    for (int i = 0; i < 16; ++i) hst[i] = 0.f;

    const int m0base = b * SEQ + c * CHUNK;
    const int xcol = hh * HEAD_DIM + dq * 64;

    for (int st = 0; st < CHUNK / SCHUNK; ++st) {
        const int m0 = m0base + st * SCHUNK;
        __syncthreads();
#pragma unroll
        for (int i = 0; i < 8; ++i) {
            int idx = t + i * 256;
            int r = idx >> 6, n = idx & 63;
            size_t rowz = (size_t)(m0 + r) * NPROJ;
            bS[r][n] = zx[rowz + OFF_B + n];
            cS[r][n] = zx[rowz + OFF_C + n];
            xS[r][n] = xh[(size_t)(m0 + r) * D_INNER + xcol + n];
        }
        if (t < SCHUNK) aS[t] = abar[(m0 + t) * N_HEADS + hh];
        __syncthreads();

        for (int r = 0; r < SCHUNK; ++r) {
            float a = aS[r];
            float xd = xS[r][d_local];
            const float* bp = &bS[r][g * 16];
            const float* cp = &cS[r][g * 16];
            float acc0 = 0.f, acc1 = 0.f;
#pragma unroll
            for (int i = 0; i < 16; i += 2) {
                hst[i]     = fmaf(a, hst[i],     bp[i]     * xd);
                acc0       = fmaf(hst[i],     cp[i],     acc0);
                hst[i + 1] = fmaf(a, hst[i + 1], bp[i + 1] * xd);
                acc1       = fmaf(hst[i + 1], cp[i + 1], acc1);
            }
            float acc = acc0 + acc1;
            acc += __shfl_xor(acc, 1);
            acc += __shfl_xor(acc, 2);
            if (g == 0)
                yscan[(size_t)(m0 + r) * D_INNER + xcol + d_local] = acc;
        }
    }

    size_t sbase = ((size_t)(bh * N_CHUNK + c) * HEAD_DIM + dq * 64 + d_local) * D_STATE + g * 16;
#pragma unroll
    for (int i = 0; i < 16; i += 4)
        *(float4*)&Sloc[sbase + i] = make_float4(hst[i], hst[i+1], hst[i+2], hst[i+3]);
}

// ---------------------------------------------------------------------------
// PASS 2: inter-chunk recurrence in place on Sloc -> H_init(c).
// ---------------------------------------------------------------------------
__global__ __launch_bounds__(256) void scan_combine_kernel(const float* __restrict__ abar,
                                                           float* __restrict__ Sloc) {
    const int blk = blockIdx.x;
    const int ds = blk & 15;
    const int bh = blk >> 4;
    const int hh = bh & (N_HEADS - 1);
    const int b  = bh >> 3;
    const int t  = threadIdx.x;

    __shared__ float PS[N_CHUNK];
    if (t < N_CHUNK) {
        float p = 1.f;
        int mbase = b * SEQ + t * CHUNK;
        for (int j = 0; j < CHUNK; ++j)
            p *= abar[(mbase + j) * N_HEADS + hh];
        PS[t] = p;
    }
    __syncthreads();

    float H[4] = {0.f, 0.f, 0.f, 0.f};
    for (int c = 0; c < N_CHUNK; ++c) {
        size_t base = (size_t)(bh * N_CHUNK + c) * STATE_PER_BH + ds * 1024 + t;
        float Sv[4];
#pragma unroll
        for (int i = 0; i < 4; ++i) Sv[i] = Sloc[base + i * 256];
#pragma unroll
        for (int i = 0; i < 4; ++i) Sloc[base + i * 256] = H[i];
        float P = PS[c];
#pragma unroll
        for (int i = 0; i < 4; ++i) H[i] = fmaf(P, H[i], Sv[i]);
    }
}

// ---------------------------------------------------------------------------
// PASS 3: y_t += cumA(t) * (C_t . H_init(chunk)).
// ---------------------------------------------------------------------------
__global__ __launch_bounds__(256) void scan_correct_kernel(const float* __restrict__ zx,
                                                           const float* __restrict__ abar,
                                                           const float* __restrict__ Hini,
                                                           float* __restrict__ yscan) {
    const int blk = blockIdx.x;
    const int dq = blk & 3;
    const int c  = (blk >> 2) & (N_CHUNK - 1);
    const int bh = blk >> 6;
    const int hh = bh & (N_HEADS - 1);
    const int b  = bh >> 3;
    const int t  = threadIdx.x;
    const int d_local = t >> 2;
    const int g = t & 3;

    __shared__ float cS[CHUNK][D_STATE];
    __shared__ float aS[CHUNK];

    const int m0 = b * SEQ + c * CHUNK;
#pragma unroll
    for (int i = 0; i < 16; ++i) {
        int idx = t + i * 256;
        int r = idx >> 6, n = idx & 63;
        cS[r][n] = zx[(size_t)(m0 + r) * NPROJ + OFF_C + n];
    }
    if (t < CHUNK) aS[t] = abar[(m0 + t) * N_HEADS + hh];

    float H[16];
    size_t hbase = ((size_t)(bh * N_CHUNK + c) * HEAD_DIM + dq * 64 + d_local) * D_STATE + g * 16;
#pragma unroll
    for (int i = 0; i < 16; i += 4) {
        float4 v = *(const float4*)&Hini[hbase + i];
        H[i] = v.x; H[i+1] = v.y; H[i+2] = v.z; H[i+3] = v.w;
    }
    __syncthreads();

    const int xcol = hh * HEAD_DIM + dq * 64;
    float cum = 1.f;
    for (int r = 0; r < CHUNK; ++r) {
        cum *= aS[r];
        const float* cp = &cS[r][g * 16];
        float acc0 = 0.f, acc1 = 0.f;
#pragma unroll
        for (int i = 0; i < 16; i += 2) {
            acc0 = fmaf(H[i],     cp[i],     acc0);
            acc1 = fmaf(H[i + 1], cp[i + 1], acc1);
        }
        float acc = acc0 + acc1;
        acc += __shfl_xor(acc, 1);
        acc += __shfl_xor(acc, 2);
        if (g == 0)
            yscan[(size_t)(m0 + r) * D_INNER + xcol + d_local] += cum * acc;
    }
}

// ---------------------------------------------------------------------------
// y = (yscan + D*xh) * silu(z); RMSNorm over D_INNER; emits bf16 hi/lo split
// directly (fused cast for GEMM2's A operand).
// ---------------------------------------------------------------------------
__global__ __launch_bounds__(256) void gate_norm_kernel(const float* __restrict__ zx,
                                                        const float* __restrict__ xh,
                                                        const float* __restrict__ Dp,
                                                        const float* __restrict__ nw,
                                                        const float* __restrict__ y,
                                                        u16* __restrict__ ybf_h,
                                                        u16* __restrict__ ybf_l) {
    const int m = blockIdx.x;
    const int t = threadIdx.x;
    const size_t rowz = (size_t)m * NPROJ;
    const size_t rowy = (size_t)m * D_INNER;

    float v[8];
    float ss = 0.f;
#pragma unroll
    for (int i = 0; i < 8; ++i) {
        int c = t + i * 256;
        float ys = fmaf(Dp[c >> 8], xh[rowy + c], y[rowy + c]);
        float z  = zx[rowz + OFF_Z + c];
        float gated = ys * (z / (1.f + expf(-z)));
        v[i] = gated;
        ss += gated * gated;
    }
#pragma unroll
    for (int off = 1; off < 64; off <<= 1) ss += __shfl_xor(ss, off);

    __shared__ float red[4];
    if ((t & 63) == 0) red[t >> 6] = ss;
    __syncthreads();
    float tot = red[0] + red[1] + red[2] + red[3];
    float scale = 1.f / sqrtf(tot / (float)D_INNER + 1e-6f);

#pragma unroll
    for (int i = 0; i < 8; ++i) {
        int c = t + i * 256;
        float o = v[i] * scale * nw[c];
        u16 h = f2bf(o);
        ybf_h[rowy + c] = h;
        ybf_l[rowy + c] = f2bf(o - bf2f(h));
    }
}

// ---------------------------------------------------------------------------
extern "C" void kernel_launch(void* const* d_in, const int* in_sizes, int n_in,
                              void* d_out, int out_size, void* d_ws, size_t ws_size,
                              hipStream_t stream) {
    const float* x         = (const float*)d_in[0];
    const float* in_proj_w = (const float*)d_in[1];
    const float* conv_w    = (const float*)d_in[2];
    const float* conv_b    = (const float*)d_in[3];
    const float* A_log     = (const float*)d_in[4];
    const float* D_param   = (const float*)d_in[5];
    const float* dt_bias   = (const float*)d_in[6];
    const float* norm_w    = (const float*)d_in[7];
    const float* out_proj_w= (const float*)d_in[8];
    float* out = (float*)d_out;

    float* ws   = (float*)d_ws;
    float* zx   = ws;                                   // M_ROWS * NPROJ fp32   (34.7 MB)
    float* xh   = zx  + (size_t)M_ROWS * NPROJ;         // M_ROWS * D_INNER fp32 (16.8 MB)
    float* ysc  = xh  + (size_t)M_ROWS * D_INNER;       // M_ROWS * D_INNER fp32 (16.8 MB)
    float* ab   = ysc + (size_t)M_ROWS * D_INNER;       // M_ROWS * N_HEADS fp32
    float* Sloc = ab  + (size_t)M_ROWS * N_HEADS;       // 4.19M fp32 (16.8 MB)

    // bf16 hi/lo overlays on regions DEAD at time of use (see launch order):
    u16* xbf_h  = (u16*)ysc;                            // ysc dead until scan pass1
    u16* xbf_l  = xbf_h + (size_t)M_ROWS * DIM;
    u16* wibf_h = (u16*)xh;                             // xh dead until conv
    u16* wibf_l = (u16*)Sloc;                           // Sloc dead until scan pass1
    u16* ybf_h  = (u16*)Sloc;                           // Sloc dead after scan pass3
    u16* ybf_l  = ybf_h + (size_t)M_ROWS * D_INNER;
    u16* wobf_h = (u16*)xh;                             // xh dead after gate_norm
    u16* wobf_l = wobf_h + (size_t)DIM * D_INNER;
    float* pbuf = zx;                                   // zx dead after gate_norm

    // split casts for GEMM1
    cast_split_kernel<<<(M_ROWS * DIM) / 1024, 256, 0, stream>>>(
        x, xbf_h, xbf_l, M_ROWS * DIM, M_ROWS * DIM);
    cast_split_kernel<<<(NPROJ_PAD * DIM) / 1024, 256, 0, stream>>>(
        in_proj_w, wibf_h, wibf_l, NPROJ * DIM, NPROJ_PAD * DIM);

    // 1) zxBCdt = x @ in_proj_w^T  (2048 x 4232, K=1024), split bf16 MFMA
    gemm_mfma3<128><<<dim3(NPROJ_PAD / 128, M_ROWS / 64, 1), 256, 0, stream>>>(
        xbf_h, xbf_l, wibf_h, wibf_l, zx, DIM, NPROJ, NPROJ, 0);

    // 2) conv + silu -> xh (+ fused dt/a_bar -> ab)
    conv_silu_kernel<<<(M_ROWS * D_INNER) / 256, 256, 0, stream>>>(
        zx, conv_w, conv_b, dt_bias, A_log, xh, ab);

    // 3) chunk-parallel scan
    scan_local_kernel<<<BATCH * N_HEADS * N_CHUNK * 4, 256, 0, stream>>>(zx, xh, ab, ysc, Sloc);
    scan_combine_kernel<<<BATCH * N_HEADS * 16, 256, 0, stream>>>(ab, Sloc);
    scan_correct_kernel<<<BATCH * N_HEADS * N_CHUNK * 4, 256, 0, stream>>>(zx, ab, Sloc, ysc);

    // 4) gate + rmsnorm, emits split-bf16 y directly
    gate_norm_kernel<<<M_ROWS, 256, 0, stream>>>(zx, xh, D_param, norm_w, ysc, ybf_h, ybf_l);

    // split cast for GEMM2 weights (xh dead now)
    cast_split_kernel<<<(DIM * D_INNER) / 1024, 256, 0, stream>>>(
        out_proj_w, wobf_h, wobf_l, DIM * D_INNER, DIM * D_INNER);

    // 5) out = y @ out_proj_w^T  (2048 x 1024, K=2048), split-K=2 -> pbuf
    gemm_mfma3<128><<<dim3(DIM / 128, M_ROWS / 64, 2), 256, 0, stream>>>(
        ybf_h, ybf_l, wobf_h, wobf_l, pbuf, D_INNER, DIM, DIM,
        (size_t)M_ROWS * DIM);

    // 6) reduce partials -> out
    reduce2_kernel<<<(M_ROWS * DIM) / 1024, 256, 0, stream>>>(pbuf, out, M_ROWS * DIM);
}